// Round 1
// baseline (526.097 us; speedup 1.0000x reference)
//
#include <hip/hip_runtime.h>
#include <hip/hip_bf16.h>

#define T_SEQ 4096
#define EMB 1024
#define NH 16
#define HD 64

typedef float f32x4 __attribute__((ext_vector_type(4)));
typedef short short8 __attribute__((ext_vector_type(8)));
typedef unsigned short ushort4v __attribute__((ext_vector_type(4)));

__device__ inline unsigned short f2bf(float f) {
  union { float f; unsigned u; } a; a.f = f;
  unsigned r = a.u + 0x7fffu + ((a.u >> 16) & 1u);
  return (unsigned short)(r >> 16);
}

// ---------------- cast x (f32 -> bf16) ----------------
__global__ __launch_bounds__(256) void cast_x_kernel(const float* __restrict__ in,
                                                     unsigned short* __restrict__ out) {
  int i = (blockIdx.x * 256 + threadIdx.x) * 8;
  float4 a = *(const float4*)(in + i);
  float4 b = *(const float4*)(in + i + 4);
  uint4 o;
  o.x = f2bf(a.x) | ((unsigned)f2bf(a.y) << 16);
  o.y = f2bf(a.z) | ((unsigned)f2bf(a.w) << 16);
  o.z = f2bf(b.x) | ((unsigned)f2bf(b.y) << 16);
  o.w = f2bf(b.z) | ((unsigned)f2bf(b.w) << 16);
  *(uint4*)(out + i) = o;
}

// ---------------- transpose + cast W (f32 [K][N] -> bf16 [N][K]) ----------------
__global__ __launch_bounds__(256) void transpose_cast_kernel(const float* __restrict__ Wq,
                                                             const float* __restrict__ Wk,
                                                             const float* __restrict__ Wv,
                                                             unsigned short* __restrict__ WTall) {
  int z = blockIdx.z;
  const float* W = (z == 0) ? Wq : ((z == 1) ? Wk : Wv);
  unsigned short* WT = WTall + (size_t)z * EMB * EMB;
  __shared__ unsigned short tile[32][33];
  int tx = threadIdx.x & 31, ty = threadIdx.x >> 5;  // 32 x 8
  int bn = blockIdx.x * 32, bk = blockIdx.y * 32;
#pragma unroll
  for (int p = 0; p < 4; p++)
    tile[ty + p * 8][tx] = f2bf(W[(size_t)(bk + ty + p * 8) * EMB + bn + tx]);
  __syncthreads();
#pragma unroll
  for (int p = 0; p < 4; p++)
    WT[(size_t)(bn + ty + p * 8) * EMB + bk + tx] = tile[tx][ty + p * 8];
}

// ---------------- QKV GEMM: [4096x1024] x [1024x1024] bf16 MFMA ----------------
// z = 0/1/2 -> Q/K/V.  Q gets the 1/8 softmax scale folded in.
__global__ __launch_bounds__(256) void gemm_qkv(const unsigned short* __restrict__ Xb,
                                                const unsigned short* __restrict__ WTall,
                                                unsigned short* __restrict__ QKV) {
  int z = blockIdx.z;
  const unsigned short* Bt = WTall + (size_t)z * EMB * EMB;
  unsigned short* Out = QKV + (size_t)z * T_SEQ * EMB;
  float scale = (z == 0) ? 0.125f : 1.0f;

  __shared__ unsigned short sA[128 * 40];  // [128 rows][32 k] pad->40
  __shared__ unsigned short sB[128 * 40];  // W^T rows (n) x k

  int m0 = blockIdx.x * 128, n0 = blockIdx.y * 128;
  int tid = threadIdx.x;
  int lane = tid & 63, wid = tid >> 6;
  int wr = wid >> 1, wc = wid & 1;  // wave -> 64x64 quadrant
  int fr = lane & 15, fq = lane >> 4;
  int ar = tid >> 2, ac = (tid & 3) * 8;  // staging: 64 rows x 4 chunks

  f32x4 acc[4][4] = {};

  for (int k0 = 0; k0 < EMB; k0 += 32) {
    short8 a0 = *(const short8*)(Xb + (size_t)(m0 + ar) * EMB + k0 + ac);
    short8 a1 = *(const short8*)(Xb + (size_t)(m0 + ar + 64) * EMB + k0 + ac);
    short8 b0 = *(const short8*)(Bt + (size_t)(n0 + ar) * EMB + k0 + ac);
    short8 b1 = *(const short8*)(Bt + (size_t)(n0 + ar + 64) * EMB + k0 + ac);
    __syncthreads();  // previous iteration's compute done
    *(short8*)(sA + ar * 40 + ac) = a0;
    *(short8*)(sA + (ar + 64) * 40 + ac) = a1;
    *(short8*)(sB + ar * 40 + ac) = b0;
    *(short8*)(sB + (ar + 64) * 40 + ac) = b1;
    __syncthreads();

    short8 aF[4], bF[4];
#pragma unroll
    for (int i = 0; i < 4; i++) {
      aF[i] = *(const short8*)(sA + (wr * 64 + i * 16 + fr) * 40 + fq * 8);
      bF[i] = *(const short8*)(sB + (wc * 64 + i * 16 + fr) * 40 + fq * 8);
    }
#pragma unroll
    for (int i = 0; i < 4; i++)
#pragma unroll
      for (int j = 0; j < 4; j++)
        acc[i][j] = __builtin_amdgcn_mfma_f32_16x16x32_bf16(aF[i], bF[j], acc[i][j], 0, 0, 0);
  }

#pragma unroll
  for (int i = 0; i < 4; i++)
#pragma unroll
    for (int j = 0; j < 4; j++)
#pragma unroll
      for (int r = 0; r < 4; r++) {
        int row = m0 + wr * 64 + i * 16 + fq * 4 + r;
        int col = n0 + wc * 64 + j * 16 + fr;
        Out[(size_t)row * EMB + col] = f2bf(acc[i][j][r] * scale);
      }
}

// ---------------- causal flash attention ----------------
// grid (T/64, NH). 4 waves; wave w owns q rows [q0+16w, q0+16w+16), full D=64.
__global__ __launch_bounds__(256) void attn_kernel(const unsigned short* __restrict__ Qb,
                                                   const unsigned short* __restrict__ Kb,
                                                   const unsigned short* __restrict__ Vb,
                                                   float* __restrict__ out) {
  int qb = blockIdx.x, h = blockIdx.y;
  int q0 = qb * 64;
  int tid = threadIdx.x, lane = tid & 63, w = tid >> 6;
  int fr = lane & 15, fq = lane >> 4;

  __shared__ unsigned short sK[32 * 72];      // K tile [32 kv][64 c] pad->72
  __shared__ unsigned short sV[64 * 40];      // V^T tile [64 c][32 kv] pad->40
  __shared__ unsigned short sP[4][16 * 40];   // per-wave P [16 q][32 kv] pad->40

  int qrow = q0 + w * 16 + fr;
  short8 qf[2];
  qf[0] = *(const short8*)(Qb + (size_t)qrow * EMB + h * HD + fq * 8);
  qf[1] = *(const short8*)(Qb + (size_t)qrow * EMB + h * HD + 32 + fq * 8);

  f32x4 o[4] = {};
  float mrow[4], lrow[4];
#pragma unroll
  for (int r = 0; r < 4; r++) { mrow[r] = -1e30f; lrow[r] = 0.f; }

  int wqmax = q0 + w * 16 + 15;
  int ntiles = (q0 + 64) / 32;

  int kr = tid >> 3, kc = (tid & 7) * 8;    // K staging: 32 rows x 8 chunks
  int vr = tid >> 4, vc = (tid & 15) * 4;   // V staging: 16 rows x 16 chunks, x2

  for (int t = 0; t < ntiles; t++) {
    int kv0 = t * 32;
    short8 kreg = *(const short8*)(Kb + (size_t)(kv0 + kr) * EMB + h * HD + kc);
    ushort4v v0 = *(const ushort4v*)(Vb + (size_t)(kv0 + vr) * EMB + h * HD + vc);
    ushort4v v1 = *(const ushort4v*)(Vb + (size_t)(kv0 + vr + 16) * EMB + h * HD + vc);
    __syncthreads();  // everyone done reading previous tile
    *(short8*)(sK + kr * 72 + kc) = kreg;
#pragma unroll
    for (int j = 0; j < 4; j++) {
      sV[(vc + j) * 40 + vr] = v0[j];
      sV[(vc + j) * 40 + vr + 16] = v1[j];
    }
    __syncthreads();

    if (kv0 <= wqmax) {  // wave-uniform causal skip
      f32x4 s[2] = {};
#pragma unroll
      for (int n = 0; n < 2; n++)
#pragma unroll
        for (int c = 0; c < 2; c++) {
          short8 kf = *(const short8*)(sK + (n * 16 + fr) * 72 + c * 32 + fq * 8);
          s[n] = __builtin_amdgcn_mfma_f32_16x16x32_bf16(qf[c], kf, s[n], 0, 0, 0);
        }
      float mt[4], al[4], ps[4];
#pragma unroll
      for (int r = 0; r < 4; r++) {
        int row = q0 + w * 16 + fq * 4 + r;
        if (kv0 + fr > row) s[0][r] = -1e30f;
        if (kv0 + 16 + fr > row) s[1][r] = -1e30f;
        mt[r] = fmaxf(s[0][r], s[1][r]);
      }
#pragma unroll
      for (int d = 1; d < 16; d <<= 1)
#pragma unroll
        for (int r = 0; r < 4; r++) mt[r] = fmaxf(mt[r], __shfl_xor(mt[r], d));
#pragma unroll
      for (int r = 0; r < 4; r++) {
        float mnew = fmaxf(mrow[r], mt[r]);
        al[r] = __expf(mrow[r] - mnew);
        float p0 = __expf(s[0][r] - mnew);
        float p1 = __expf(s[1][r] - mnew);
        mrow[r] = mnew;
        s[0][r] = p0; s[1][r] = p1;
        ps[r] = p0 + p1;
      }
#pragma unroll
      for (int d = 1; d < 16; d <<= 1)
#pragma unroll
        for (int r = 0; r < 4; r++) ps[r] += __shfl_xor(ps[r], d);
#pragma unroll
      for (int r = 0; r < 4; r++) lrow[r] = lrow[r] * al[r] + ps[r];

      unsigned short* pw = sP[w];
#pragma unroll
      for (int n = 0; n < 2; n++)
#pragma unroll
        for (int r = 0; r < 4; r++)
          pw[(fq * 4 + r) * 40 + n * 16 + fr] = f2bf(s[n][r]);
#pragma unroll
      for (int d = 0; d < 4; d++)
#pragma unroll
        for (int r = 0; r < 4; r++) o[d][r] *= al[r];

      asm volatile("s_waitcnt lgkmcnt(0)" ::: "memory");  // wave-local P round-trip
      short8 pf = *(const short8*)(pw + fr * 40 + fq * 8);
#pragma unroll
      for (int d = 0; d < 4; d++) {
        short8 vf = *(const short8*)(sV + (d * 16 + fr) * 40 + fq * 8);
        o[d] = __builtin_amdgcn_mfma_f32_16x16x32_bf16(pf, vf, o[d], 0, 0, 0);
      }
    }
  }

#pragma unroll
  for (int d = 0; d < 4; d++)
#pragma unroll
    for (int r = 0; r < 4; r++) {
      int row = q0 + w * 16 + fq * 4 + r;
      out[(size_t)row * EMB + h * HD + d * 16 + fr] = o[d][r] / lrow[r];
    }
}

extern "C" void kernel_launch(void* const* d_in, const int* in_sizes, int n_in,
                              void* d_out, int out_size, void* d_ws, size_t ws_size,
                              hipStream_t stream) {
  const float* x  = (const float*)d_in[0];
  const float* Wq = (const float*)d_in[1];
  const float* Wk = (const float*)d_in[2];
  const float* Wv = (const float*)d_in[3];
  float* out = (float*)d_out;

  unsigned short* Qb = (unsigned short*)d_ws;
  unsigned short* Kb = Qb + (size_t)T_SEQ * EMB;
  unsigned short* Vb = Kb + (size_t)T_SEQ * EMB;
  unsigned short* Xb = Vb + (size_t)T_SEQ * EMB;
  unsigned short* WT = Xb + (size_t)T_SEQ * EMB;  // 3 x EMB*EMB bf16

  cast_x_kernel<<<(T_SEQ * EMB) / (256 * 8), 256, 0, stream>>>(x, Xb);
  dim3 tg(EMB / 32, EMB / 32, 3);
  transpose_cast_kernel<<<tg, 256, 0, stream>>>(Wq, Wk, Wv, WT);
  dim3 gg(T_SEQ / 128, EMB / 128, 3);
  gemm_qkv<<<gg, 256, 0, stream>>>(Xb, WT, Qb);
  dim3 ag(T_SEQ / 64, NH);
  attn_kernel<<<ag, 256, 0, stream>>>(Qb, Kb, Vb, out);
}

// Round 4
// 258.585 us; speedup vs baseline: 2.0345x; 2.0345x over previous
//
#include <hip/hip_runtime.h>
#include <hip/hip_bf16.h>

#define T_SEQ 4096
#define EMB 1024
#define NH 16
#define HD 64
#define QBLK 128
#define KVB 64
#define DEFER_THR 10.0f

typedef float f32x4 __attribute__((ext_vector_type(4)));
typedef float f32x16 __attribute__((ext_vector_type(16)));
typedef short short8 __attribute__((ext_vector_type(8)));
typedef short short4v __attribute__((ext_vector_type(4)));

__device__ inline unsigned short f2bf(float f) {
  union { float f; unsigned u; } a; a.f = f;
  unsigned r = a.u + 0x7fffu + ((a.u >> 16) & 1u);
  return (unsigned short)(r >> 16);
}
#if __has_builtin(__builtin_amdgcn_exp2f)
#define EXP2F(x) __builtin_amdgcn_exp2f(x)
#else
#define EXP2F(x) exp2f(x)
#endif
#define GLL16(g, l) __builtin_amdgcn_global_load_lds( \
    (const __attribute__((address_space(1))) void*)(g), \
    (__attribute__((address_space(3))) void*)(l), 16, 0, 0)

// ---------------- cast x (f32 -> bf16) ----------------
__global__ __launch_bounds__(256) void cast_x_kernel(const float* __restrict__ in,
                                                     unsigned short* __restrict__ out) {
  int i = (blockIdx.x * 256 + threadIdx.x) * 8;
  float4 a = *(const float4*)(in + i);
  float4 b = *(const float4*)(in + i + 4);
  uint4 o;
  o.x = f2bf(a.x) | ((unsigned)f2bf(a.y) << 16);
  o.y = f2bf(a.z) | ((unsigned)f2bf(a.w) << 16);
  o.z = f2bf(b.x) | ((unsigned)f2bf(b.y) << 16);
  o.w = f2bf(b.z) | ((unsigned)f2bf(b.w) << 16);
  *(uint4*)(out + i) = o;
}

// ---------------- transpose + cast W (f32 [K][N] -> bf16 [N][K]) ----------------
__global__ __launch_bounds__(256) void transpose_cast_kernel(const float* __restrict__ Wq,
                                                             const float* __restrict__ Wk,
                                                             const float* __restrict__ Wv,
                                                             unsigned short* __restrict__ WTall) {
  int z = blockIdx.z;
  const float* W = (z == 0) ? Wq : ((z == 1) ? Wk : Wv);
  unsigned short* WT = WTall + (size_t)z * EMB * EMB;
  __shared__ unsigned short tile[32][33];
  int tx = threadIdx.x & 31, ty = threadIdx.x >> 5;
  int bn = blockIdx.x * 32, bk = blockIdx.y * 32;
#pragma unroll
  for (int p = 0; p < 4; p++)
    tile[ty + p * 8][tx] = f2bf(W[(size_t)(bk + ty + p * 8) * EMB + bn + tx]);
  __syncthreads();
#pragma unroll
  for (int p = 0; p < 4; p++)
    WT[(size_t)(bn + ty + p * 8) * EMB + bk + tx] = tile[tx][ty + p * 8];
}

// ---------------- QKV GEMM (m97-style global_load_lds staging) ----------------
// z=0 -> Q (scaled by 0.125*log2e), z=1 -> K, z=2 -> V written TRANSPOSED as VT[1024][4096]
__global__ __launch_bounds__(256) void gemm_qkv(const unsigned short* __restrict__ Xb,
                                                const unsigned short* __restrict__ WTall,
                                                unsigned short* __restrict__ QKV) {
  int z = blockIdx.z;
  const unsigned short* Bt = WTall + (size_t)z * EMB * EMB;
  unsigned short* Out = QKV + (size_t)z * T_SEQ * EMB;

  __shared__ __align__(16) unsigned short sA[128 * 32];
  __shared__ __align__(16) unsigned short sB[128 * 32];

  int m0 = blockIdx.x * 128, n0 = blockIdx.y * 128;
  int tid = threadIdx.x;
  int lane = tid & 63, wid = tid >> 6;
  int wr = wid >> 1, wc = wid & 1;
  int fr = lane & 15, fq = lane >> 4;

  int r0 = tid >> 2, o0 = (tid & 3) * 8;
  int r1 = (tid + 256) >> 2;

  f32x4 acc[4][4] = {};

  for (int k0 = 0; k0 < EMB; k0 += 32) {
    __syncthreads();
    GLL16(Xb + (size_t)(m0 + r0) * EMB + k0 + o0, sA + (size_t)tid * 8);
    GLL16(Xb + (size_t)(m0 + r1) * EMB + k0 + o0, sA + (size_t)(tid + 256) * 8);
    GLL16(Bt + (size_t)(n0 + r0) * EMB + k0 + o0, sB + (size_t)tid * 8);
    GLL16(Bt + (size_t)(n0 + r1) * EMB + k0 + o0, sB + (size_t)(tid + 256) * 8);
    asm volatile("s_waitcnt vmcnt(0)" ::: "memory");
    __syncthreads();

    short8 aF[4], bF[4];
#pragma unroll
    for (int i = 0; i < 4; i++) {
      aF[i] = *(const short8*)(sA + (wr * 64 + i * 16 + fr) * 32 + fq * 8);
      bF[i] = *(const short8*)(sB + (wc * 64 + i * 16 + fr) * 32 + fq * 8);
    }
#pragma unroll
    for (int i = 0; i < 4; i++)
#pragma unroll
      for (int j = 0; j < 4; j++)
        acc[i][j] = __builtin_amdgcn_mfma_f32_16x16x32_bf16(aF[i], bF[j], acc[i][j], 0, 0, 0);
  }

  if (z == 2) {
    // write V transposed: VT[dall][t]
#pragma unroll
    for (int i = 0; i < 4; i++)
#pragma unroll
      for (int j = 0; j < 4; j++) {
        int col = n0 + wc * 64 + j * 16 + fr;        // dall
        int row0 = m0 + wr * 64 + i * 16 + fq * 4;   // t
        short4v pk4;
#pragma unroll
        for (int r = 0; r < 4; r++) pk4[r] = (short)f2bf(acc[i][j][r]);
        *(short4v*)(Out + (size_t)col * T_SEQ + row0) = pk4;
      }
  } else {
    float scale = (z == 0) ? 0.1803368801111204f : 1.0f;  // 0.125 * log2(e) for Q
#pragma unroll
    for (int i = 0; i < 4; i++)
#pragma unroll
      for (int j = 0; j < 4; j++)
#pragma unroll
        for (int r = 0; r < 4; r++) {
          int row = m0 + wr * 64 + i * 16 + fq * 4 + r;
          int col = n0 + wc * 64 + j * 16 + fr;
          Out[(size_t)row * EMB + col] = f2bf(acc[i][j][r] * scale);
        }
  }
}

// ---------------- causal flash attention, swapped-QK 32x32x16 ----------------
// grid (32, 16) reversed-x; 4 waves x 32 q-rows = 128 q per block; KVB=64.
__global__ __launch_bounds__(256) void attn_kernel(const unsigned short* __restrict__ Qb,
                                                   const unsigned short* __restrict__ Kb,
                                                   const unsigned short* __restrict__ VTg,
                                                   float* __restrict__ out) {
  int qb = (gridDim.x - 1) - blockIdx.x;  // long blocks dispatch first
  int h = blockIdx.y;
  int q0 = qb * QBLK;
  int tid = threadIdx.x;
  int lane = tid & 63, w = tid >> 6;
  int ql = lane & 31, hi = lane >> 5;

  __shared__ __align__(16) unsigned short smem[14336];  // 28672 B
  unsigned short* sK = smem;                      // [64][72]
  unsigned short* sVT = smem + 64 * 72;           // [64][72] (V^T: [d][kv])
  unsigned short* sP = smem + 2 * 64 * 72 + w * (32 * 40);  // per-wave [32 q][32 kv] pad 40

  int wq0 = q0 + w * 32;
  int qg = wq0 + ql;

  short8 qf[4];  // B-frags of Q: Q[q=ql][d = ks*16 + hi*8 + j]
#pragma unroll
  for (int ks = 0; ks < 4; ks++)
    qf[ks] = *(const short8*)(Qb + (size_t)qg * EMB + h * HD + ks * 16 + hi * 8);

  f32x16 oT0 = {}, oT1 = {};  // O^T accumulators, d-tiles 0/1, col = q = ql
  float m = -1e30f, lsum = 0.f;

  // staging: 8 lanes x 16B = one 128B row; rows sr and sr+32
  int sr = tid >> 3;            // 0..31
  int scs = (tid & 7) * 8;      // col offset in shorts

  int wqmax = wq0 + 31;
  int ntiles = (q0 + QBLK) / KVB;

  for (int t = 0; t < ntiles; t++) {
    int kv0 = t * KVB;
    short8 ka = *(const short8*)(Kb + (size_t)(kv0 + sr) * EMB + h * HD + scs);
    short8 kb = *(const short8*)(Kb + (size_t)(kv0 + sr + 32) * EMB + h * HD + scs);
    short8 va = *(const short8*)(VTg + (size_t)(h * HD + sr) * T_SEQ + kv0 + scs);
    short8 vb = *(const short8*)(VTg + (size_t)(h * HD + sr + 32) * T_SEQ + kv0 + scs);
    __syncthreads();
    *(short8*)(sK + sr * 72 + scs) = ka;
    *(short8*)(sK + (sr + 32) * 72 + scs) = kb;
    *(short8*)(sVT + sr * 72 + scs) = va;
    *(short8*)(sVT + (sr + 32) * 72 + scs) = vb;
    __syncthreads();

#pragma unroll
    for (int s = 0; s < 2; s++) {
      int kvs = kv0 + s * 32;
      if (kvs <= wqmax) {  // wave-uniform causal skip
        f32x16 st = {};
        __builtin_amdgcn_s_setprio(1);
#pragma unroll
        for (int ks = 0; ks < 4; ks++) {
          short8 kf = *(const short8*)(sK + (s * 32 + ql) * 72 + ks * 16 + hi * 8);
          st = __builtin_amdgcn_mfma_f32_32x32x16_bf16(kf, qf[ks], st, 0, 0, 0);
        }
        __builtin_amdgcn_s_setprio(0);
        if (kvs + 31 > wq0) {  // diagonal tile: mask kv > q
#pragma unroll
          for (int r = 0; r < 16; r++) {
            int kvg = kvs + (r & 3) + 8 * (r >> 2) + 4 * hi;
            if (kvg > qg) st[r] = -1e30f;
          }
        }
        float mt = st[0];
#pragma unroll
        for (int r = 1; r < 16; r++) mt = fmaxf(mt, st[r]);
        mt = fmaxf(mt, __shfl_xor(mt, 32));
        if (!__all(mt - m <= DEFER_THR)) {  // defer-max (T13)
          float mnew = fmaxf(m, mt);
          float al = EXP2F(m - mnew);
          lsum *= al;
#pragma unroll
          for (int r = 0; r < 16; r++) { oT0[r] *= al; oT1[r] *= al; }
          m = mnew;
        }
#pragma unroll
        for (int r = 0; r < 16; r++) st[r] = EXP2F(st[r] - m);
        float ls = st[0];
#pragma unroll
        for (int r = 1; r < 16; r++) ls += st[r];
        ls += __shfl_xor(ls, 32);
        lsum += ls;

        // P^T -> bf16 via per-wave LDS round-trip: sP[q=ql][kv_local]
        // st[r] = P[kv_local = (r&3) + 8*(r>>2) + 4*hi][q=ql]; groups of 4 contiguous
#pragma unroll
        for (int g = 0; g < 4; g++) {
          short4v pk4;
#pragma unroll
          for (int r4 = 0; r4 < 4; r4++) pk4[r4] = (short)f2bf(st[g * 4 + r4]);
          *(short4v*)(sP + ql * 40 + g * 8 + hi * 4) = pk4;
        }
        asm volatile("s_waitcnt lgkmcnt(0)" ::: "memory");  // wave-local round-trip
        __builtin_amdgcn_sched_barrier(0);

        __builtin_amdgcn_s_setprio(1);
#pragma unroll
        for (int ksp = 0; ksp < 2; ksp++) {
          // B-frag: P[k = ksp*16 + hi*8 + j][col = ql]
          short8 pa = *(const short8*)(sP + ql * 40 + ksp * 16 + hi * 8);
          int cb = s * 32 + ksp * 16 + hi * 8;  // kv col in sVT (shorts)
          short8 v0 = *(const short8*)(sVT + (0 * 32 + ql) * 72 + cb);
          short8 v1 = *(const short8*)(sVT + (1 * 32 + ql) * 72 + cb);
          oT0 = __builtin_amdgcn_mfma_f32_32x32x16_bf16(v0, pa, oT0, 0, 0, 0);
          oT1 = __builtin_amdgcn_mfma_f32_32x32x16_bf16(v1, pa, oT1, 0, 0, 0);
        }
        __builtin_amdgcn_s_setprio(0);
      }
    }
  }

  // epilogue: divide, transpose O^T -> O through LDS, coalesced f32x4 stores
  float inv = 1.0f / lsum;
  float* sw = (float*)smem + w * (32 * 36);
  int orow = lane >> 1, ocol = (lane & 1) * 16;
#pragma unroll
  for (int dt = 0; dt < 2; dt++) {
    __syncthreads();
#pragma unroll
    for (int r = 0; r < 16; r++) {
      int dl = (r & 3) + 8 * (r >> 2) + 4 * hi;
      sw[ql * 36 + dl] = (dt ? oT1[r] : oT0[r]) * inv;
    }
    __syncthreads();
#pragma unroll
    for (int c = 0; c < 4; c++) {
      f32x4 vv = *(const f32x4*)(sw + orow * 36 + ocol + c * 4);
      *(f32x4*)(out + (size_t)(wq0 + orow) * EMB + h * HD + dt * 32 + ocol + c * 4) = vv;
    }
  }
}

extern "C" void kernel_launch(void* const* d_in, const int* in_sizes, int n_in,
                              void* d_out, int out_size, void* d_ws, size_t ws_size,
                              hipStream_t stream) {
  const float* x  = (const float*)d_in[0];
  const float* Wq = (const float*)d_in[1];
  const float* Wk = (const float*)d_in[2];
  const float* Wv = (const float*)d_in[3];
  float* out = (float*)d_out;

  unsigned short* Qb = (unsigned short*)d_ws;
  unsigned short* Kb = Qb + (size_t)T_SEQ * EMB;
  unsigned short* VT = Kb + (size_t)T_SEQ * EMB;   // VT[1024][4096]
  unsigned short* Xb = VT + (size_t)T_SEQ * EMB;
  unsigned short* WT = Xb + (size_t)T_SEQ * EMB;   // 3 x EMB*EMB bf16

  cast_x_kernel<<<(T_SEQ * EMB) / (256 * 8), 256, 0, stream>>>(x, Xb);
  dim3 tg(EMB / 32, EMB / 32, 3);
  transpose_cast_kernel<<<tg, 256, 0, stream>>>(Wq, Wk, Wv, WT);
  dim3 gg(T_SEQ / 128, EMB / 128, 3);
  gemm_qkv<<<gg, 256, 0, stream>>>(Xb, WT, Qb);
  dim3 ag(T_SEQ / QBLK, NH);
  attn_kernel<<<ag, 256, 0, stream>>>(Qb, Kb, VT, out);
}

// Round 5
// 250.967 us; speedup vs baseline: 2.0963x; 1.0304x over previous
//
#include <hip/hip_runtime.h>
#include <hip/hip_bf16.h>

#define T_SEQ 4096
#define EMB 1024
#define NH 16
#define HD 64
#define QBLK 128
#define KVB 64
#define DEFER_THR 10.0f

typedef float f32x4 __attribute__((ext_vector_type(4)));
typedef float f32x16 __attribute__((ext_vector_type(16)));
typedef short short8 __attribute__((ext_vector_type(8)));
typedef short short4v __attribute__((ext_vector_type(4)));

__device__ inline unsigned short f2bf(float f) {
  union { float f; unsigned u; } a; a.f = f;
  unsigned r = a.u + 0x7fffu + ((a.u >> 16) & 1u);
  return (unsigned short)(r >> 16);
}
#if __has_builtin(__builtin_amdgcn_exp2f)
#define EXP2F(x) __builtin_amdgcn_exp2f(x)
#else
#define EXP2F(x) exp2f(x)
#endif
#define GLL16(g, l) __builtin_amdgcn_global_load_lds( \
    (const __attribute__((address_space(1))) void*)(g), \
    (__attribute__((address_space(3))) void*)(l), 16, 0, 0)

// ---------------- cast x (f32 -> bf16) ----------------
__global__ __launch_bounds__(256) void cast_x_kernel(const float* __restrict__ in,
                                                     unsigned short* __restrict__ out) {
  int i = (blockIdx.x * 256 + threadIdx.x) * 8;
  float4 a = *(const float4*)(in + i);
  float4 b = *(const float4*)(in + i + 4);
  uint4 o;
  o.x = f2bf(a.x) | ((unsigned)f2bf(a.y) << 16);
  o.y = f2bf(a.z) | ((unsigned)f2bf(a.w) << 16);
  o.z = f2bf(b.x) | ((unsigned)f2bf(b.y) << 16);
  o.w = f2bf(b.z) | ((unsigned)f2bf(b.w) << 16);
  *(uint4*)(out + i) = o;
}

// ---------------- transpose + cast W (f32 [K][N] -> bf16 [N][K]) ----------------
__global__ __launch_bounds__(256) void transpose_cast_kernel(const float* __restrict__ Wq,
                                                             const float* __restrict__ Wk,
                                                             const float* __restrict__ Wv,
                                                             unsigned short* __restrict__ WTall) {
  int z = blockIdx.z;
  const float* W = (z == 0) ? Wq : ((z == 1) ? Wk : Wv);
  unsigned short* WT = WTall + (size_t)z * EMB * EMB;
  __shared__ unsigned short tile[32][33];
  int tx = threadIdx.x & 31, ty = threadIdx.x >> 5;
  int bn = blockIdx.x * 32, bk = blockIdx.y * 32;
#pragma unroll
  for (int p = 0; p < 4; p++)
    tile[ty + p * 8][tx] = f2bf(W[(size_t)(bk + ty + p * 8) * EMB + bn + tx]);
  __syncthreads();
#pragma unroll
  for (int p = 0; p < 4; p++)
    WT[(size_t)(bn + ty + p * 8) * EMB + bk + tx] = tile[tx][ty + p * 8];
}

// ---------------- QKV GEMM (m97-style global_load_lds staging) ----------------
// z=0 -> Q (scaled by 0.125*log2e), z=1 -> K, z=2 -> V written TRANSPOSED as VT[1024][4096]
__global__ __launch_bounds__(256) void gemm_qkv(const unsigned short* __restrict__ Xb,
                                                const unsigned short* __restrict__ WTall,
                                                unsigned short* __restrict__ QKV) {
  int z = blockIdx.z;
  const unsigned short* Bt = WTall + (size_t)z * EMB * EMB;
  unsigned short* Out = QKV + (size_t)z * T_SEQ * EMB;

  __shared__ __align__(16) unsigned short sA[128 * 32];
  __shared__ __align__(16) unsigned short sB[128 * 32];

  int m0 = blockIdx.x * 128, n0 = blockIdx.y * 128;
  int tid = threadIdx.x;
  int lane = tid & 63, wid = tid >> 6;
  int wr = wid >> 1, wc = wid & 1;
  int fr = lane & 15, fq = lane >> 4;

  int r0 = tid >> 2, o0 = (tid & 3) * 8;
  int r1 = (tid + 256) >> 2;

  f32x4 acc[4][4] = {};

  for (int k0 = 0; k0 < EMB; k0 += 32) {
    __syncthreads();
    GLL16(Xb + (size_t)(m0 + r0) * EMB + k0 + o0, sA + (size_t)tid * 8);
    GLL16(Xb + (size_t)(m0 + r1) * EMB + k0 + o0, sA + (size_t)(tid + 256) * 8);
    GLL16(Bt + (size_t)(n0 + r0) * EMB + k0 + o0, sB + (size_t)tid * 8);
    GLL16(Bt + (size_t)(n0 + r1) * EMB + k0 + o0, sB + (size_t)(tid + 256) * 8);
    asm volatile("s_waitcnt vmcnt(0)" ::: "memory");
    __syncthreads();

    short8 aF[4], bF[4];
#pragma unroll
    for (int i = 0; i < 4; i++) {
      aF[i] = *(const short8*)(sA + (wr * 64 + i * 16 + fr) * 32 + fq * 8);
      bF[i] = *(const short8*)(sB + (wc * 64 + i * 16 + fr) * 32 + fq * 8);
    }
#pragma unroll
    for (int i = 0; i < 4; i++)
#pragma unroll
      for (int j = 0; j < 4; j++)
        acc[i][j] = __builtin_amdgcn_mfma_f32_16x16x32_bf16(aF[i], bF[j], acc[i][j], 0, 0, 0);
  }

  if (z == 2) {
    // write V transposed: VT[dall][t]
#pragma unroll
    for (int i = 0; i < 4; i++)
#pragma unroll
      for (int j = 0; j < 4; j++) {
        int col = n0 + wc * 64 + j * 16 + fr;        // dall
        int row0 = m0 + wr * 64 + i * 16 + fq * 4;   // t
        short4v pk4;
#pragma unroll
        for (int r = 0; r < 4; r++) pk4[r] = (short)f2bf(acc[i][j][r]);
        *(short4v*)(Out + (size_t)col * T_SEQ + row0) = pk4;
      }
  } else {
    float scale = (z == 0) ? 0.1803368801111204f : 1.0f;  // 0.125 * log2(e) for Q
#pragma unroll
    for (int i = 0; i < 4; i++)
#pragma unroll
      for (int j = 0; j < 4; j++)
#pragma unroll
        for (int r = 0; r < 4; r++) {
          int row = m0 + wr * 64 + i * 16 + fq * 4 + r;
          int col = n0 + wc * 64 + j * 16 + fr;
          Out[(size_t)row * EMB + col] = f2bf(acc[i][j][r] * scale);
        }
  }
}

// ---------------- causal flash attention, swapped-QK 32x32x16 ----------------
// grid (32, 16) reversed-x; 4 waves x 32 q-rows = 128 q per block; KVB=64.
// T14 software pipeline: K/V loads for tile t+1 issued before compute of tile t.
__global__ __launch_bounds__(256) void attn_kernel(const unsigned short* __restrict__ Qb,
                                                   const unsigned short* __restrict__ Kb,
                                                   const unsigned short* __restrict__ VTg,
                                                   float* __restrict__ out) {
  int qb = (gridDim.x - 1) - blockIdx.x;  // long blocks dispatch first
  int h = blockIdx.y;
  int q0 = qb * QBLK;
  int tid = threadIdx.x;
  int lane = tid & 63, w = tid >> 6;
  int ql = lane & 31, hi = lane >> 5;

  __shared__ __align__(16) unsigned short smem[14336];  // 28672 B
  unsigned short* sK = smem;                      // [64][72]
  unsigned short* sVT = smem + 64 * 72;           // [64][72] (V^T: [d][kv])
  unsigned short* sP = smem + 2 * 64 * 72 + w * (32 * 40);  // per-wave [32 q][32 kv] pad 40

  int wq0 = q0 + w * 32;
  int qg = wq0 + ql;

  short8 qf[4];  // B-frags of Q: Q[q=ql][d = ks*16 + hi*8 + j]
#pragma unroll
  for (int ks = 0; ks < 4; ks++)
    qf[ks] = *(const short8*)(Qb + (size_t)qg * EMB + h * HD + ks * 16 + hi * 8);

  f32x16 oT0 = {}, oT1 = {};  // O^T accumulators, d-tiles 0/1, col = q = ql
  float m = -1e30f, lsum = 0.f;

  // staging: 8 lanes x 16B = one 128B row; rows sr and sr+32
  int sr = tid >> 3;            // 0..31
  int scs = (tid & 7) * 8;      // col offset in shorts

  int wqmax = wq0 + 31;
  int ntiles = (q0 + QBLK) / KVB;

  // prologue: issue loads for tile 0
  short8 ka = *(const short8*)(Kb + (size_t)(sr) * EMB + h * HD + scs);
  short8 kb = *(const short8*)(Kb + (size_t)(sr + 32) * EMB + h * HD + scs);
  short8 va = *(const short8*)(VTg + (size_t)(h * HD + sr) * T_SEQ + scs);
  short8 vb = *(const short8*)(VTg + (size_t)(h * HD + sr + 32) * T_SEQ + scs);

  for (int t = 0; t < ntiles; t++) {
    int kv0 = t * KVB;
    __syncthreads();  // all waves done reading previous tile
    *(short8*)(sK + sr * 72 + scs) = ka;
    *(short8*)(sK + (sr + 32) * 72 + scs) = kb;
    *(short8*)(sVT + sr * 72 + scs) = va;
    *(short8*)(sVT + (sr + 32) * 72 + scs) = vb;
    __syncthreads();  // publish

    if (t + 1 < ntiles) {  // issue next tile's loads; latency hides under compute
      int kv1 = kv0 + KVB;
      ka = *(const short8*)(Kb + (size_t)(kv1 + sr) * EMB + h * HD + scs);
      kb = *(const short8*)(Kb + (size_t)(kv1 + sr + 32) * EMB + h * HD + scs);
      va = *(const short8*)(VTg + (size_t)(h * HD + sr) * T_SEQ + kv1 + scs);
      vb = *(const short8*)(VTg + (size_t)(h * HD + sr + 32) * T_SEQ + kv1 + scs);
    }

#pragma unroll
    for (int s = 0; s < 2; s++) {
      int kvs = kv0 + s * 32;
      if (kvs <= wqmax) {  // wave-uniform causal skip
        f32x16 st = {};
        __builtin_amdgcn_s_setprio(1);
#pragma unroll
        for (int ks = 0; ks < 4; ks++) {
          short8 kf = *(const short8*)(sK + (s * 32 + ql) * 72 + ks * 16 + hi * 8);
          st = __builtin_amdgcn_mfma_f32_32x32x16_bf16(kf, qf[ks], st, 0, 0, 0);
        }
        __builtin_amdgcn_s_setprio(0);
        if (kvs + 31 > wq0) {  // diagonal tile: mask kv > q
#pragma unroll
          for (int r = 0; r < 16; r++) {
            int kvg = kvs + (r & 3) + 8 * (r >> 2) + 4 * hi;
            if (kvg > qg) st[r] = -1e30f;
          }
        }
        // max-reduce as max3-friendly tree
        float a0 = fmaxf(fmaxf(st[0], st[1]), st[2]);
        float a1 = fmaxf(fmaxf(st[3], st[4]), st[5]);
        float a2 = fmaxf(fmaxf(st[6], st[7]), st[8]);
        float a3 = fmaxf(fmaxf(st[9], st[10]), st[11]);
        float a4 = fmaxf(fmaxf(st[12], st[13]), st[14]);
        float mt = fmaxf(fmaxf(fmaxf(a0, a1), a2), fmaxf(fmaxf(a3, a4), st[15]));
        mt = fmaxf(mt, __shfl_xor(mt, 32));
        if (!__all(mt - m <= DEFER_THR)) {  // defer-max (T13)
          float mnew = fmaxf(m, mt);
          float al = EXP2F(m - mnew);
          lsum *= al;
#pragma unroll
          for (int r = 0; r < 16; r++) { oT0[r] *= al; oT1[r] *= al; }
          m = mnew;
        }
#pragma unroll
        for (int r = 0; r < 16; r++) st[r] = EXP2F(st[r] - m);
        // pairwise sum tree
        float s0 = (st[0] + st[1]) + (st[2] + st[3]);
        float s1 = (st[4] + st[5]) + (st[6] + st[7]);
        float s2 = (st[8] + st[9]) + (st[10] + st[11]);
        float s3 = (st[12] + st[13]) + (st[14] + st[15]);
        float ls = (s0 + s1) + (s2 + s3);
        ls += __shfl_xor(ls, 32);
        lsum += ls;

        // P^T -> bf16 via per-wave LDS round-trip: sP[q=ql][kv_local]
        // st[r] = P[kv_local = (r&3) + 8*(r>>2) + 4*hi][q=ql]; groups of 4 contiguous
#pragma unroll
        for (int g = 0; g < 4; g++) {
          __hip_bfloat162 plo = __float22bfloat162_rn(float2{st[g * 4 + 0], st[g * 4 + 1]});
          __hip_bfloat162 phi = __float22bfloat162_rn(float2{st[g * 4 + 2], st[g * 4 + 3]});
          union { __hip_bfloat162 h[2]; short4v s4; } u4;
          u4.h[0] = plo; u4.h[1] = phi;
          *(short4v*)(sP + ql * 40 + g * 8 + hi * 4) = u4.s4;
        }
        asm volatile("s_waitcnt lgkmcnt(0)" ::: "memory");  // wave-local round-trip
        __builtin_amdgcn_sched_barrier(0);

        __builtin_amdgcn_s_setprio(1);
#pragma unroll
        for (int ksp = 0; ksp < 2; ksp++) {
          // B-frag: P[k = ksp*16 + hi*8 + j][col = ql]
          short8 pa = *(const short8*)(sP + ql * 40 + ksp * 16 + hi * 8);
          int cb = s * 32 + ksp * 16 + hi * 8;  // kv col in sVT (shorts)
          short8 v0 = *(const short8*)(sVT + (0 * 32 + ql) * 72 + cb);
          short8 v1 = *(const short8*)(sVT + (1 * 32 + ql) * 72 + cb);
          oT0 = __builtin_amdgcn_mfma_f32_32x32x16_bf16(v0, pa, oT0, 0, 0, 0);
          oT1 = __builtin_amdgcn_mfma_f32_32x32x16_bf16(v1, pa, oT1, 0, 0, 0);
        }
        __builtin_amdgcn_s_setprio(0);
      }
    }
  }

  // epilogue: divide, transpose O^T -> O through LDS, coalesced f32x4 stores
  float inv = 1.0f / lsum;
  float* sw = (float*)smem + w * (32 * 36);
  int orow = lane >> 1, ocol = (lane & 1) * 16;
#pragma unroll
  for (int dt = 0; dt < 2; dt++) {
    __syncthreads();
#pragma unroll
    for (int r = 0; r < 16; r++) {
      int dl = (r & 3) + 8 * (r >> 2) + 4 * hi;
      sw[ql * 36 + dl] = (dt ? oT1[r] : oT0[r]) * inv;
    }
    __syncthreads();
#pragma unroll
    for (int c = 0; c < 4; c++) {
      f32x4 vv = *(const f32x4*)(sw + orow * 36 + ocol + c * 4);
      *(f32x4*)(out + (size_t)(wq0 + orow) * EMB + h * HD + dt * 32 + ocol + c * 4) = vv;
    }
  }
}

extern "C" void kernel_launch(void* const* d_in, const int* in_sizes, int n_in,
                              void* d_out, int out_size, void* d_ws, size_t ws_size,
                              hipStream_t stream) {
  const float* x  = (const float*)d_in[0];
  const float* Wq = (const float*)d_in[1];
  const float* Wk = (const float*)d_in[2];
  const float* Wv = (const float*)d_in[3];
  float* out = (float*)d_out;

  unsigned short* Qb = (unsigned short*)d_ws;
  unsigned short* Kb = Qb + (size_t)T_SEQ * EMB;
  unsigned short* VT = Kb + (size_t)T_SEQ * EMB;   // VT[1024][4096]
  unsigned short* Xb = VT + (size_t)T_SEQ * EMB;
  unsigned short* WT = Xb + (size_t)T_SEQ * EMB;   // 3 x EMB*EMB bf16

  cast_x_kernel<<<(T_SEQ * EMB) / (256 * 8), 256, 0, stream>>>(x, Xb);
  dim3 tg(EMB / 32, EMB / 32, 3);
  transpose_cast_kernel<<<tg, 256, 0, stream>>>(Wq, Wk, Wv, WT);
  dim3 gg(T_SEQ / 128, EMB / 128, 3);
  gemm_qkv<<<gg, 256, 0, stream>>>(Xb, WT, Qb);
  dim3 ag(T_SEQ / QBLK, NH);
  attn_kernel<<<ag, 256, 0, stream>>>(Qb, Kb, VT, out);
}